// Round 6
// baseline (663.697 us; speedup 1.0000x reference)
//
#include <hip/hip_runtime.h>
#include <stdint.h>

#define IN_DIM 8192
#define OUT_DIM 4096
#define NNZ 1638400
#define BATCH 4096

typedef __bf16 bf16x8 __attribute__((ext_vector_type(8)));
typedef float f32x4 __attribute__((ext_vector_type(4)));

// ---- helpers ----------------------------------------------------------------

__device__ __forceinline__ unsigned short f2bf(float f) {
  union { float f; unsigned int u; } v; v.f = f;
  unsigned int u = v.u;
  unsigned int r = (u + 0x7FFFu + ((u >> 16) & 1u)) >> 16;  // RNE
  return (unsigned short)r;
}

__device__ __forceinline__ float bf2f(unsigned short b) {
  union { unsigned int u; float f; } v;
  v.u = (unsigned int)b << 16;
  return v.f;
}

__device__ __forceinline__ void async16(const void* g, void* l) {
  __builtin_amdgcn_global_load_lds(
      (const __attribute__((address_space(1))) unsigned int*)g,
      (__attribute__((address_space(3))) unsigned int*)l,
      16, 0, 0);
}

__device__ __forceinline__ void convert_body(int i, const float* __restrict__ src,
                                             unsigned short* __restrict__ dst) {
  const float4* s = (const float4*)src;
  float4 a = s[2 * i];
  float4 b = s[2 * i + 1];
  union { unsigned short us[8]; uint4 v; } o;
  o.us[0] = f2bf(a.x); o.us[1] = f2bf(a.y); o.us[2] = f2bf(a.z); o.us[3] = f2bf(a.w);
  o.us[4] = f2bf(b.x); o.us[5] = f2bf(b.y); o.us[6] = f2bf(b.z); o.us[7] = f2bf(b.w);
  ((uint4*)dst)[i] = o.v;
}

// ---- kernel 1: zero W_bf16 + convert x (unchanged since R0) -----------------

#define PREP_BLOCKS ((IN_DIM * OUT_DIM) / 8 / 256)  // 16384

__global__ void prep_kernel(uint4* __restrict__ W_zero,
                            const float* __restrict__ x,
                            unsigned short* __restrict__ x_bf16) {
  int i = blockIdx.x * 256 + threadIdx.x;
  W_zero[i] = make_uint4(0, 0, 0, 0);
  convert_body(i, x, x_bf16);
}

// ---- kernel 2: scatter-add into bf16 W via 32-bit CAS (unchanged) -----------

__device__ __forceinline__ void scat1(int c, int r, float w,
                                      unsigned int* __restrict__ W) {
  size_t e = (size_t)c * IN_DIM + r;     // element index in W^T [OUT][IN]
  unsigned int* p = W + (e >> 1);
  const bool hi = (e & 1);
  unsigned int cur = *p;                 // seed (CAS corrects staleness)
  unsigned int assumed;
  do {
    assumed = cur;
    unsigned short h = hi ? (unsigned short)(assumed >> 16)
                          : (unsigned short)(assumed & 0xFFFFu);
    unsigned short nb = f2bf(bf2f(h) + w);
    unsigned int nw = hi ? ((assumed & 0x0000FFFFu) | ((unsigned int)nb << 16))
                         : ((assumed & 0xFFFF0000u) | (unsigned int)nb);
    cur = atomicCAS(p, assumed, nw);
  } while (cur != assumed);
}

#define SCAT_BLOCKS (NNZ / 4 / 256)  // 1600

__global__ void scatter_kernel(const int4* __restrict__ ri4,
                               const int4* __restrict__ ci4,
                               const float4* __restrict__ w4,
                               unsigned int* __restrict__ W) {
  int i = blockIdx.x * 256 + threadIdx.x;
  int4 r = ri4[i];
  int4 c = ci4[i];
  float4 w = w4[i];
  scat1(c.x, r.x, w.x, W);
  scat1(c.y, r.y, w.y, W);
  scat1(c.z, r.z, w.z, W);
  scat1(c.w, r.w, w.w, W);
}

// ---- kernel 3: bf16 GEMM, 256x256, 8 waves, boundary-pipelined --------------
// R4/R5 barrier-light + ONE structural change: register-level tile-ahead
// prefetch. Per tile t:
//   top barrier (nbuf dead) -> burst-stage t+1 -> q0..q2 MFMA (q0 frags
//   already in regs from prev tile) -> vmcnt(0) [t+1's loads ~3000cyc old]
//   -> mid barrier (t+1 visible) -> prefetch t+1's B-frags + q0 A-frags
//   under q3's MFMA shadow -> q3 MFMA.
// Matrix pipe never drains across the tile boundary; the 12-read post-
// barrier ramp that stalled all 8 barrier-synced waves at once is gone.
// Race audit:
//  - top barrier: every wave's reads of nbuf (prev tile's main af reads,
//    consumed by its MFMAs via lgkm waits) completed before arrival ->
//    staging overwrite safe.
//  - mid vmcnt(0)+barrier: only t+1's 8 loads outstanding (t's were drained
//    at t-1's mid); after the barrier t+1's LDS data is visible to all ->
//    prefetch reads safe. Stage target (buf_t parity at t+1 top) never
//    aliases the prefetch-read buffer (buf_{t+1} parity) within a tile.

#define TBM 256
#define TBN 256
#define TBK 64
#define NKT (IN_DIM / TBK)  // 128

__global__ __launch_bounds__(512, 2) void gemm_kernel(
    const unsigned short* __restrict__ A,   // [BATCH][IN_DIM] bf16 bits
    const unsigned short* __restrict__ Bt,  // [OUT_DIM][IN_DIM] bf16 bits
    const float* __restrict__ bias,         // [OUT_DIM]
    float* __restrict__ C) {                // [BATCH][OUT_DIM] fp32
  extern __shared__ __align__(16) unsigned short lds[];  // 131072 B

  const int tid = threadIdx.x;

  // XCD-region swizzle: 8m x 4n block region per XCD (R5, kept: -100MB HBM).
  const int bid = blockIdx.x;
  const int xcd = bid & 7;
  const int jb = bid >> 3;
  const int m0 = ((xcd & 1) * 8 + (jb & 7)) * TBM;
  const int n0 = ((xcd >> 1) * 4 + (jb >> 3)) * TBN;

  const int wid = tid >> 6;
  const int lane = tid & 63;
  const int wm = wid >> 2;       // 0..1
  const int wn = wid & 3;        // 0..3
  const int quad = lane >> 4;
  const int lm = lane & 15;
  const int xorv = lm & 7;

  const unsigned short* Ab = A + (size_t)m0 * IN_DIM;
  const unsigned short* Bb = Bt + (size_t)n0 * IN_DIM;

  // staging geometry: tile = 256 rows x 8 segs of 16B; 512 thr -> 4 rounds.
  int soff[4], ldst[4];
#pragma unroll
  for (int c = 0; c < 4; ++c) {
    const int t2 = c * 512 + tid;
    const int srow = t2 >> 3;
    const int sgs = (t2 & 7) ^ (srow & 7);    // stage-side swizzle
    soff[c] = srow * IN_DIM + sgs * 8;
    ldst[c] = t2 * 16;                         // LDS byte offset (linear dest)
  }

  f32x4 acc[8][4] = {};

#define STAGE(kt_, b_, c_)                                                  \
  do {                                                                      \
    const int k0_ = (kt_)*TBK;                                              \
    char* la_ = (char*)lds + (b_)*65536;                                    \
    async16(Ab + (size_t)soff[c_] + k0_, la_ + ldst[c_]);                   \
    async16(Bb + (size_t)soff[c_] + k0_, la_ + 32768 + ldst[c_]);           \
  } while (0)

#define RD_AF(lAp_, q_, AFD)                                                \
  do {                                                                      \
    _Pragma("unroll") for (int i = 0; i < 2; ++i) {                         \
      const int row = wm * 128 + ((q_)*2 + i) * 16 + lm;                    \
      _Pragma("unroll") for (int ss = 0; ss < 2; ++ss) {                    \
        const int p = ((ss << 2) | quad) ^ xorv;                            \
        AFD[i][ss] = *(const bf16x8*)((lAp_) + row * TBK + p * 8);          \
      }                                                                     \
    }                                                                       \
  } while (0)

#define RD_BF(lBp_, BFD)                                                    \
  do {                                                                      \
    _Pragma("unroll") for (int j2 = 0; j2 < 4; ++j2) {                      \
      const int row = wn * 64 + j2 * 16 + lm;                               \
      _Pragma("unroll") for (int ss = 0; ss < 2; ++ss) {                    \
        const int p = ((ss << 2) | quad) ^ xorv;                            \
        BFD[j2][ss] = *(const bf16x8*)((lBp_) + row * TBK + p * 8);         \
      }                                                                     \
    }                                                                       \
  } while (0)

#define MFMA_Q(q_, AF, BFR)                                                 \
  do {                                                                      \
    __builtin_amdgcn_s_setprio(1);                                          \
    _Pragma("unroll") for (int i = 0; i < 2; ++i)                           \
    _Pragma("unroll") for (int j2 = 0; j2 < 4; ++j2)                        \
    _Pragma("unroll") for (int ss = 0; ss < 2; ++ss)                        \
      acc[(q_)*2 + i][j2] = __builtin_amdgcn_mfma_f32_16x16x32_bf16(        \
          AF[i][ss], BFR[j2][ss], acc[(q_)*2 + i][j2], 0, 0, 0);            \
    __builtin_amdgcn_s_setprio(0);                                          \
  } while (0)

// One tile with boundary pipelining. Entry: tile t's B-frags in BFRC, q0
// A-frags in AFC, buf_{t} visible. Exit: tile t+1's frags in BFRN/AFN.
#define TILE(t_, buf_, BFRC, AFC, BFRN, AFN)                                \
  do {                                                                      \
    const int nb_ = (buf_) ^ 1;                                             \
    const int ktn_ = ((t_) + 1) & (NKT - 1);                                \
    const unsigned short* lA_ = lds + (buf_)*32768;                         \
    /* top barrier: nbuf provably dead -> stage t+1 into it */              \
    __builtin_amdgcn_sched_barrier(0);                                      \
    __builtin_amdgcn_s_barrier();                                           \
    __builtin_amdgcn_sched_barrier(0);                                      \
    _Pragma("unroll") for (int c = 0; c < 4; ++c) STAGE(ktn_, nb_, c);      \
    /* q0 fires immediately from registers */                               \
    MFMA_Q(0, AFC, BFRC);                                                   \
    {                                                                       \
      bf16x8 afx[2][2];                                                     \
      RD_AF(lA_, 1, afx);                                                   \
      MFMA_Q(1, afx, BFRC);                                                 \
    }                                                                       \
    {                                                                       \
      bf16x8 afx[2][2];                                                     \
      RD_AF(lA_, 2, afx);                                                   \
      MFMA_Q(2, afx, BFRC);                                                 \
    }                                                                       \
    {                                                                       \
      bf16x8 afx[2][2];                                                     \
      RD_AF(lA_, 3, afx);                                                   \
      /* mid fence: t+1's 8 loads (aged ~3000cyc) drained + visible */      \
      asm volatile("s_waitcnt vmcnt(0)" ::: "memory");                      \
      __builtin_amdgcn_sched_barrier(0);                                    \
      __builtin_amdgcn_s_barrier();                                         \
      __builtin_amdgcn_sched_barrier(0);                                    \
      /* prefetch t+1 frags under q3's MFMA shadow */                       \
      RD_BF(lds + nb_*32768 + 16384, BFRN);                                 \
      RD_AF(lds + nb_*32768, 0, AFN);                                       \
      MFMA_Q(3, afx, BFRC);                                                 \
    }                                                                       \
  } while (0)

  // prologue: stage K-tile 0 into buf 0; make visible; pre-read its frags.
#pragma unroll
  for (int c = 0; c < 4; ++c) STAGE(0, 0, c);
  asm volatile("s_waitcnt vmcnt(0)" ::: "memory");
  __builtin_amdgcn_sched_barrier(0);
  __builtin_amdgcn_s_barrier();
  __builtin_amdgcn_sched_barrier(0);
  bf16x8 bfrP[4][2], bfrQ[4][2], afP[2][2], afQ[2][2];
  RD_BF(lds + 16384, bfrP);
  RD_AF(lds, 0, afP);

  for (int kt = 0; kt < NKT; kt += 2) {
    TILE(kt, 0, bfrP, afP, bfrQ, afQ);
    TILE(kt + 1, 1, bfrQ, afQ, bfrP, afP);
  }

#undef TILE
#undef MFMA_Q
#undef RD_BF
#undef RD_AF
#undef STAGE

  // retire the wrap-around tail loads before LDS deallocation / endpgm.
  asm volatile("s_waitcnt vmcnt(0)" ::: "memory");

  // Epilogue: C/D layout col = lane&15, row = quad*4 + reg  [m89-verified]
  const int ccol0 = n0 + wn * 64 + lm;
  const int crow0 = m0 + wm * 128;
#pragma unroll
  for (int j2 = 0; j2 < 4; ++j2) {
    const int col = ccol0 + j2 * 16;
    const float bv = bias[col];
#pragma unroll
    for (int i = 0; i < 8; ++i) {
#pragma unroll
      for (int v = 0; v < 4; ++v) {
        const int row = crow0 + i * 16 + quad * 4 + v;
        C[(size_t)row * OUT_DIM + col] = acc[i][j2][v] + bv;
      }
    }
  }
}

// ---- launch -----------------------------------------------------------------

extern "C" void kernel_launch(void* const* d_in, const int* in_sizes, int n_in,
                              void* d_out, int out_size, void* d_ws, size_t ws_size,
                              hipStream_t stream) {
  const float* x = (const float*)d_in[0];       // [4096][8192] fp32
  const int* row_idx = (const int*)d_in[1];     // [NNZ] int32
  const int* col_idx = (const int*)d_in[2];     // [NNZ] int32
  const float* weights = (const float*)d_in[3]; // [NNZ] fp32
  const float* bias = (const float*)d_in[4];    // [4096] fp32
  float* out = (float*)d_out;                   // [4096][4096] fp32

  // ws layout: W_bf16 [0,64M), x_bf16 [64M,128M).
  const size_t W_BF16_BYTES = (size_t)IN_DIM * OUT_DIM * 2;  // 64 MiB
  unsigned short* W_bf16 = (unsigned short*)d_ws;
  unsigned short* x_bf16 = (unsigned short*)((char*)d_ws + W_BF16_BYTES);

  static bool attr_set = false;
  if (!attr_set) {
    (void)hipFuncSetAttribute((const void*)gemm_kernel,
                              hipFuncAttributeMaxDynamicSharedMemorySize,
                              131072);
    attr_set = true;
  }

  // 1. zero W_bf16 + convert x -> bf16
  prep_kernel<<<PREP_BLOCKS, 256, 0, stream>>>((uint4*)W_bf16, x, x_bf16);

  // 2. scatter-add weights directly into bf16 W^T (CAS)
  scatter_kernel<<<SCAT_BLOCKS, 256, 0, stream>>>(
      (const int4*)row_idx, (const int4*)col_idx, (const float4*)weights,
      (unsigned int*)W_bf16);

  // 3. GEMM + bias (256^2 tile, 8 waves, XCD-region-swizzled grid of 256)
  gemm_kernel<<<dim3(256), dim3(512), 131072, stream>>>(x_bf16, W_bf16, bias, out);
}